// Round 2
// baseline (369.478 us; speedup 1.0000x reference)
//
#include <hip/hip_runtime.h>

typedef __bf16 bf16x8 __attribute__((ext_vector_type(8)));
typedef float f32x4 __attribute__((ext_vector_type(4)));
typedef unsigned short u16x4 __attribute__((ext_vector_type(4)));
typedef unsigned short u16x8 __attribute__((ext_vector_type(8)));

#define NBATCH 8
#define LPTS   16384
#define CDIM   256
#define KANC   64
#define DIN    512
#define H1DIM  128
#define H2DIM  256
#define TM     64

__device__ __forceinline__ unsigned short f2b(float f){
  __bf16 h = (__bf16)f;                 // native v_cvt, RNE
  return __builtin_bit_cast(unsigned short, h);
}

// wt[0..65536) = W1T[128][512]; wt[65536..98304) = W2T[256][128];
// wt[98304..163840) = W3T[256][256]   (all bf16)
__global__ __launch_bounds__(256) void prep_weights(
    const float* __restrict__ W1, const float* __restrict__ W2,
    const float* __restrict__ W3, unsigned short* __restrict__ wt){
  int id = blockIdx.x * 256 + threadIdx.x;
  if (id < 65536){
    int r = id >> 9, c = id & 511;
    wt[id] = f2b(W1[c * 128 + r]);
  } else if (id < 98304){
    int t = id - 65536; int r = t >> 7, c = t & 127;
    wt[id] = f2b(W2[c * 256 + r]);
  } else if (id < 163840){
    int t = id - 98304; int r = t >> 8, c = t & 255;
    wt[id] = f2b(W3[c * 256 + r]);
  }
}

__global__ __launch_bounds__(512, 4) void fused(
    const float* __restrict__ feat0, const float* __restrict__ feat1,
    const float* __restrict__ pts0, const float* __restrict__ pts1,
    const int* __restrict__ anc_i, const int* __restrict__ anc_j,
    const float* __restrict__ b1, const float* __restrict__ b2,
    const float* __restrict__ b3, const unsigned short* __restrict__ wt,
    float* __restrict__ out)
{
  // 80 KiB -> 2 blocks/CU. h2s aliases xs (dead after GEMM1);
  // anc4 aliases h1s (dead before h1s first written).
  __shared__ unsigned short xs[TM * DIN];     // 64 KiB
  __shared__ unsigned short h1s[TM * H1DIM];  // 16 KiB
  unsigned short* h2s = xs;
  float4* anc4 = (float4*)h1s;                // 1 KiB

  const int tid  = threadIdx.x;
  const int wg   = blockIdx.x;
  const int strm = wg >> 11;
  const int n    = (wg >> 8) & 7;
  const int l0   = (wg & 255) * TM;

  const float* feat = strm ? feat1 : feat0;
  const float* pts  = strm ? pts1 : pts0;
  const int*   anci = strm ? anc_j : anc_i;

  // ---- prefetch feat tile into registers (latency hides under Phase B)
  const float4* fb = (const float4*)(feat + ((size_t)n * LPTS + l0) * CDIM);
  float4 fv[8];
  #pragma unroll
  for (int it = 0; it < 4; ++it){
    int chunk = it * 512 + tid;         // 8-float chunk, 2048 per tile
    fv[it*2]   = fb[chunk * 2];
    fv[it*2+1] = fb[chunk * 2 + 1];
  }

  // ---- anchors -> LDS (float4)
  if (tid < KANC){
    int ai = anci[n * KANC + tid];
    const float* pp = pts + ((size_t)n * LPTS + ai) * 3;
    anc4[tid] = make_float4(pp[0], pp[1], pp[2], 0.f);
  }
  __syncthreads();

  // ---- Phase B pass 1: partial L1 sums (8 threads/point, 8 anchors each)
  const int l   = tid >> 3;             // point in tile
  const int sub = tid & 7;              // anchor-octet
  const float* pp = pts + ((size_t)n * LPTS + l0 + l) * 3;
  float px = pp[0], py = pp[1], pz = pp[2];
  float s0 = 0.f, s1 = 0.f, s2 = 0.f, s3 = 0.f;
  #pragma unroll
  for (int i = 0; i < 8; ++i){
    float4 a = anc4[sub * 8 + i];
    float dx = px - a.x, dy = py - a.y, dz = pz - a.z;
    float d2 = dx*dx + dy*dy + dz*dz;
    s0 += fabsf(dx); s1 += fabsf(dy); s2 += fabsf(dz); s3 += d2;
  }
  #pragma unroll
  for (int m = 1; m <= 4; m <<= 1){
    s0 += __shfl_xor(s0, m, 64);
    s1 += __shfl_xor(s1, m, 64);
    s2 += __shfl_xor(s2, m, 64);
    s3 += __shfl_xor(s3, m, 64);
  }
  float i0 = 1.f/s0, i1 = 1.f/s1, i2 = 1.f/s2, i3 = 1.f/s3;

  // ---- feat regs -> xs[:,0:256) (frees the 32 prefetch VGPRs)
  #pragma unroll
  for (int it = 0; it < 4; ++it){
    int chunk = it * 512 + tid;
    int r = chunk >> 5, c8 = chunk & 31;
    float4 a = fv[it*2], b = fv[it*2+1];
    u16x8 pk = { f2b(a.x), f2b(a.y), f2b(a.z), f2b(a.w),
                 f2b(b.x), f2b(b.y), f2b(b.z), f2b(b.w) };
    int e = (r * DIN + c8 * 8) ^ ((r & 7) << 3);
    *(u16x8*)&xs[e] = pk;
  }

  // ---- Phase B pass 2: normalized values -> xs[:,256:512)
  {
    u16x8 o0, o1, o2, o3;
    #pragma unroll
    for (int i = 0; i < 8; ++i){
      float4 a = anc4[sub * 8 + i];
      float dx = px - a.x, dy = py - a.y, dz = pz - a.z;
      float d2 = dx*dx + dy*dy + dz*dz;
      o0[i] = f2b(dx * i0); o1[i] = f2b(dy * i1);
      o2[i] = f2b(dz * i2); o3[i] = f2b(d2 * i3);
    }
    int base = l * DIN + 256 + sub * 8;
    int sw = (l & 7) << 3;
    *(u16x8*)&xs[(base      ) ^ sw] = o0;
    *(u16x8*)&xs[(base +  64) ^ sw] = o1;
    *(u16x8*)&xs[(base + 128) ^ sw] = o2;
    *(u16x8*)&xs[(base + 192) ^ sw] = o3;
  }
  __syncthreads();

  // ---- GEMM wave grid: 2M x 4N
  const int lane = tid & 63;
  const int w    = tid >> 6;
  const int wr   = w >> 2, wc = w & 3;
  const int lr   = lane & 15, lg = lane >> 4;
  const int r0   = wr * 32;
  const int sw   = (lr & 7) << 3;       // A-read swizzle (row&7 == lr&7)

  // ---- GEMM1: xs[64,512] @ W1 -> relu -> h1s[64,128]
  {
    f32x4 acc[2][2] = {};
    #pragma unroll 4
    for (int kk = 0; kk < 16; ++kk){
      int kb = kk * 32 + lg * 8;
      bf16x8 a0 = *(const bf16x8*)&xs[((r0      + lr) * DIN + kb) ^ sw];
      bf16x8 a1 = *(const bf16x8*)&xs[((r0 + 16 + lr) * DIN + kb) ^ sw];
      bf16x8 b0 = *(const bf16x8*)&wt[(wc * 32      + lr) * DIN + kb];
      bf16x8 b1f = *(const bf16x8*)&wt[(wc * 32 + 16 + lr) * DIN + kb];
      acc[0][0] = __builtin_amdgcn_mfma_f32_16x16x32_bf16(a0, b0,  acc[0][0], 0, 0, 0);
      acc[0][1] = __builtin_amdgcn_mfma_f32_16x16x32_bf16(a0, b1f, acc[0][1], 0, 0, 0);
      acc[1][0] = __builtin_amdgcn_mfma_f32_16x16x32_bf16(a1, b0,  acc[1][0], 0, 0, 0);
      acc[1][1] = __builtin_amdgcn_mfma_f32_16x16x32_bf16(a1, b1f, acc[1][1], 0, 0, 0);
    }
    #pragma unroll
    for (int nn = 0; nn < 2; ++nn){
      int col = wc * 32 + nn * 16 + lr;
      float bias = b1[col];
      #pragma unroll
      for (int m = 0; m < 2; ++m){
        #pragma unroll
        for (int r = 0; r < 4; ++r){
          int row = r0 + m * 16 + lg * 4 + r;
          float v = fmaxf(acc[m][nn][r] + bias, 0.f);
          h1s[(row * H1DIM + col) ^ ((row & 7) << 3)] = f2b(v);
        }
      }
    }
  }
  __syncthreads();

  // ---- GEMM2: h1s[64,128] @ W2 -> relu -> h2s[64,256]
  {
    const unsigned short* w2t = wt + 65536;
    f32x4 acc[2][4] = {};
    #pragma unroll
    for (int kk = 0; kk < 4; ++kk){
      int kb = kk * 32 + lg * 8;
      bf16x8 a0 = *(const bf16x8*)&h1s[((r0      + lr) * H1DIM + kb) ^ sw];
      bf16x8 a1 = *(const bf16x8*)&h1s[((r0 + 16 + lr) * H1DIM + kb) ^ sw];
      #pragma unroll
      for (int nn = 0; nn < 4; ++nn){
        bf16x8 b = *(const bf16x8*)&w2t[(wc * 64 + nn * 16 + lr) * H1DIM + kb];
        acc[0][nn] = __builtin_amdgcn_mfma_f32_16x16x32_bf16(a0, b, acc[0][nn], 0, 0, 0);
        acc[1][nn] = __builtin_amdgcn_mfma_f32_16x16x32_bf16(a1, b, acc[1][nn], 0, 0, 0);
      }
    }
    #pragma unroll
    for (int nn = 0; nn < 4; ++nn){
      int col = wc * 64 + nn * 16 + lr;
      float bias = b2[col];
      #pragma unroll
      for (int m = 0; m < 2; ++m){
        #pragma unroll
        for (int r = 0; r < 4; ++r){
          int row = r0 + m * 16 + lg * 4 + r;
          float v = fmaxf(acc[m][nn][r] + bias, 0.f);
          h2s[(row * H2DIM + col) ^ ((row & 7) << 3)] = f2b(v);
        }
      }
    }
  }
  __syncthreads();

  // ---- GEMM3: h2s[64,256] @ W3 -> + b3 -> out (f32)
  {
    const unsigned short* w3t = wt + 98304;
    f32x4 acc[2][4] = {};
    #pragma unroll 4
    for (int kk = 0; kk < 8; ++kk){
      int kb = kk * 32 + lg * 8;
      bf16x8 a0 = *(const bf16x8*)&h2s[((r0      + lr) * H2DIM + kb) ^ sw];
      bf16x8 a1 = *(const bf16x8*)&h2s[((r0 + 16 + lr) * H2DIM + kb) ^ sw];
      #pragma unroll
      for (int nn = 0; nn < 4; ++nn){
        bf16x8 b = *(const bf16x8*)&w3t[(wc * 64 + nn * 16 + lr) * H2DIM + kb];
        acc[0][nn] = __builtin_amdgcn_mfma_f32_16x16x32_bf16(a0, b, acc[0][nn], 0, 0, 0);
        acc[1][nn] = __builtin_amdgcn_mfma_f32_16x16x32_bf16(a1, b, acc[1][nn], 0, 0, 0);
      }
    }
    float* ob = out + (((size_t)strm * NBATCH + n) * LPTS + l0) * CDIM;
    #pragma unroll
    for (int nn = 0; nn < 4; ++nn){
      int col = wc * 64 + nn * 16 + lr;
      float bias = b3[col];
      #pragma unroll
      for (int m = 0; m < 2; ++m){
        #pragma unroll
        for (int r = 0; r < 4; ++r){
          int row = r0 + m * 16 + lg * 4 + r;
          ob[row * CDIM + col] = acc[m][nn][r] + bias;
        }
      }
    }
  }
}

extern "C" void kernel_launch(void* const* d_in, const int* in_sizes, int n_in,
                              void* d_out, int out_size, void* d_ws, size_t ws_size,
                              hipStream_t stream){
  const float* feat0 = (const float*)d_in[0];
  const float* feat1 = (const float*)d_in[1];
  const float* pts0  = (const float*)d_in[2];
  const float* pts1  = (const float*)d_in[3];
  const int*   anci  = (const int*)d_in[4];
  const int*   ancj  = (const int*)d_in[5];
  const float* W1    = (const float*)d_in[6];
  const float* b1    = (const float*)d_in[7];
  const float* W2    = (const float*)d_in[8];
  const float* b2    = (const float*)d_in[9];
  const float* W3    = (const float*)d_in[10];
  const float* b3    = (const float*)d_in[11];
  unsigned short* wt = (unsigned short*)d_ws;
  float* out = (float*)d_out;

  prep_weights<<<640, 256, 0, stream>>>(W1, W2, W3, wt);
  fused<<<4096, 512, 0, stream>>>(feat0, feat1, pts0, pts1, anci, ancj,
                                  b1, b2, b3, wt, out);
}

// Round 3
// 360.151 us; speedup vs baseline: 1.0259x; 1.0259x over previous
//
#include <hip/hip_runtime.h>

typedef __bf16 bf16x8 __attribute__((ext_vector_type(8)));
typedef float f32x4 __attribute__((ext_vector_type(4)));
typedef unsigned short u16x8 __attribute__((ext_vector_type(8)));

#define NBATCH 8
#define LPTS   16384
#define CDIM   256
#define KANC   64
#define DIN    512
#define H1DIM  128
#define H2DIM  256
#define TM     32

__device__ __forceinline__ unsigned short f2b(float f){
  __bf16 h = (__bf16)f;                 // native v_cvt, RNE
  return __builtin_bit_cast(unsigned short, h);
}

// wt[0..65536) = W1T[128][512]; wt[65536..98304) = W2T[256][128];
// wt[98304..163840) = W3T[256][256]   (all bf16)
__global__ __launch_bounds__(256) void prep_weights(
    const float* __restrict__ W1, const float* __restrict__ W2,
    const float* __restrict__ W3, unsigned short* __restrict__ wt){
  int id = blockIdx.x * 256 + threadIdx.x;
  if (id < 65536){
    int r = id >> 9, c = id & 511;
    wt[id] = f2b(W1[c * 128 + r]);
  } else if (id < 98304){
    int t = id - 65536; int r = t >> 7, c = t & 127;
    wt[id] = f2b(W2[c * 256 + r]);
  } else if (id < 163840){
    int t = id - 98304; int r = t >> 8, c = t & 255;
    wt[id] = f2b(W3[c * 256 + r]);
  }
}

// TM=32, 256 threads (4 waves), LDS 40 KiB -> 4 blocks/CU.
__global__ __launch_bounds__(256, 4) void fused(
    const float* __restrict__ feat0, const float* __restrict__ feat1,
    const float* __restrict__ pts0, const float* __restrict__ pts1,
    const int* __restrict__ anc_i, const int* __restrict__ anc_j,
    const float* __restrict__ b1, const float* __restrict__ b2,
    const float* __restrict__ b3, const unsigned short* __restrict__ wt,
    float* __restrict__ out)
{
  __shared__ unsigned short xs[TM * DIN];     // 32 KiB
  __shared__ unsigned short h1s[TM * H1DIM];  // 8 KiB
  unsigned short* h2s = xs;                   // xs dead (as input) after G1 reads
  float4* anc4 = (float4*)h1s;                // dead before h1s first written

  const int tid  = threadIdx.x;
  const int wg   = blockIdx.x;
  const int strm = wg >> 12;
  const int n    = (wg >> 9) & 7;
  const int l0   = (wg & 511) * TM;

  const float* feat = strm ? feat1 : feat0;
  const float* pts  = strm ? pts1 : pts0;
  const int*   anci = strm ? anc_j : anc_i;

  // ---- anchors -> LDS
  if (tid < KANC){
    int ai = anci[n * KANC + tid];
    const float* pp = pts + ((size_t)n * LPTS + ai) * 3;
    anc4[tid] = make_float4(pp[0], pp[1], pp[2], 0.f);
  }

  // ---- Phase A: feat tile -> xs[:,0:256) (streamed, swizzled 16B stores)
  {
    const float4* fb = (const float4*)(feat + ((size_t)n * LPTS + l0) * CDIM);
    #pragma unroll
    for (int it = 0; it < 4; ++it){
      int chunk = it * 256 + tid;       // 1024 8-float chunks per tile
      int r = chunk >> 5, c8 = chunk & 31;
      float4 a = fb[chunk * 2], b = fb[chunk * 2 + 1];
      u16x8 pk = { f2b(a.x), f2b(a.y), f2b(a.z), f2b(a.w),
                   f2b(b.x), f2b(b.y), f2b(b.z), f2b(b.w) };
      int e = (r * DIN + c8 * 8) ^ ((r & 7) << 3);
      *(u16x8*)&xs[e] = pk;
    }
  }
  __syncthreads();

  // ---- Phase B: structured features -> xs[:,256:512)
  // 8 threads/point, 8 anchors each; 3-level shfl_xor for the L1 sums.
  {
    const int l   = tid >> 3;           // 0..31
    const int sub = tid & 7;
    const float* pp = pts + ((size_t)n * LPTS + l0 + l) * 3;
    float px = pp[0], py = pp[1], pz = pp[2];
    float s0 = 0.f, s1 = 0.f, s2 = 0.f, s3 = 0.f;
    #pragma unroll
    for (int i = 0; i < 8; ++i){
      float4 a = anc4[sub * 8 + i];
      float dx = px - a.x, dy = py - a.y, dz = pz - a.z;
      float d2 = dx*dx + dy*dy + dz*dz;
      s0 += fabsf(dx); s1 += fabsf(dy); s2 += fabsf(dz); s3 += d2;
    }
    #pragma unroll
    for (int m = 1; m <= 4; m <<= 1){
      s0 += __shfl_xor(s0, m, 64);
      s1 += __shfl_xor(s1, m, 64);
      s2 += __shfl_xor(s2, m, 64);
      s3 += __shfl_xor(s3, m, 64);
    }
    float i0 = 1.f/s0, i1 = 1.f/s1, i2 = 1.f/s2, i3 = 1.f/s3;

    u16x8 o0, o1, o2, o3;
    #pragma unroll
    for (int i = 0; i < 8; ++i){
      float4 a = anc4[sub * 8 + i];
      float dx = px - a.x, dy = py - a.y, dz = pz - a.z;
      float d2 = dx*dx + dy*dy + dz*dz;
      o0[i] = f2b(dx * i0); o1[i] = f2b(dy * i1);
      o2[i] = f2b(dz * i2); o3[i] = f2b(d2 * i3);
    }
    int base = l * DIN + 256 + sub * 8;
    int sw = (l & 7) << 3;
    *(u16x8*)&xs[(base      ) ^ sw] = o0;
    *(u16x8*)&xs[(base +  64) ^ sw] = o1;
    *(u16x8*)&xs[(base + 128) ^ sw] = o2;
    *(u16x8*)&xs[(base + 192) ^ sw] = o3;
  }
  __syncthreads();

  // ---- GEMMs: 4 waves, each spans full M (2 frags), owns 1/4 of N
  const int lane = tid & 63;
  const int w    = tid >> 6;            // 0..3
  const int lr   = lane & 15, lg = lane >> 4;
  const int sw   = (lr & 7) << 3;

  // ---- GEMM1: xs[32,512] @ W1 -> relu -> h1s[32,128]; wave cols w*32..+32
  {
    f32x4 acc[2][2] = {};
    const unsigned short* bpA = wt + (w * 32      + lr) * DIN;
    const unsigned short* bpB = wt + (w * 32 + 16 + lr) * DIN;
    #pragma unroll
    for (int kk = 0; kk < 16; ++kk){
      int kb = kk * 32 + lg * 8;
      bf16x8 a0 = *(const bf16x8*)&xs[((     lr) * DIN + kb) ^ sw];
      bf16x8 a1 = *(const bf16x8*)&xs[((16 + lr) * DIN + kb) ^ sw];
      bf16x8 b0 = *(const bf16x8*)&bpA[kb];
      bf16x8 b1f = *(const bf16x8*)&bpB[kb];
      acc[0][0] = __builtin_amdgcn_mfma_f32_16x16x32_bf16(a0, b0,  acc[0][0], 0, 0, 0);
      acc[0][1] = __builtin_amdgcn_mfma_f32_16x16x32_bf16(a0, b1f, acc[0][1], 0, 0, 0);
      acc[1][0] = __builtin_amdgcn_mfma_f32_16x16x32_bf16(a1, b0,  acc[1][0], 0, 0, 0);
      acc[1][1] = __builtin_amdgcn_mfma_f32_16x16x32_bf16(a1, b1f, acc[1][1], 0, 0, 0);
    }
    #pragma unroll
    for (int nn = 0; nn < 2; ++nn){
      int col = w * 32 + nn * 16 + lr;
      float bias = b1[col];
      #pragma unroll
      for (int m = 0; m < 2; ++m){
        #pragma unroll
        for (int r = 0; r < 4; ++r){
          int row = m * 16 + lg * 4 + r;
          float v = fmaxf(acc[m][nn][r] + bias, 0.f);
          h1s[(row * H1DIM + col) ^ ((row & 7) << 3)] = f2b(v);
        }
      }
    }
  }
  __syncthreads();

  // ---- GEMM2: h1s[32,128] @ W2 -> relu -> h2s[32,256]; wave cols w*64..+64
  {
    const unsigned short* w2t = wt + 65536;
    f32x4 acc[2][4] = {};
    #pragma unroll
    for (int kk = 0; kk < 4; ++kk){
      int kb = kk * 32 + lg * 8;
      bf16x8 a0 = *(const bf16x8*)&h1s[((     lr) * H1DIM + kb) ^ sw];
      bf16x8 a1 = *(const bf16x8*)&h1s[((16 + lr) * H1DIM + kb) ^ sw];
      #pragma unroll
      for (int nn = 0; nn < 4; ++nn){
        bf16x8 b = *(const bf16x8*)&w2t[(w * 64 + nn * 16 + lr) * H1DIM + kb];
        acc[0][nn] = __builtin_amdgcn_mfma_f32_16x16x32_bf16(a0, b, acc[0][nn], 0, 0, 0);
        acc[1][nn] = __builtin_amdgcn_mfma_f32_16x16x32_bf16(a1, b, acc[1][nn], 0, 0, 0);
      }
    }
    __syncthreads();   // G1's xs reads retired before h2s(=xs) writes
    #pragma unroll
    for (int nn = 0; nn < 4; ++nn){
      int col = w * 64 + nn * 16 + lr;
      float bias = b2[col];
      #pragma unroll
      for (int m = 0; m < 2; ++m){
        #pragma unroll
        for (int r = 0; r < 4; ++r){
          int row = m * 16 + lg * 4 + r;
          float v = fmaxf(acc[m][nn][r] + bias, 0.f);
          h2s[(row * H2DIM + col) ^ ((row & 7) << 3)] = f2b(v);
        }
      }
    }
  }
  __syncthreads();

  // ---- GEMM3: h2s[32,256] @ W3 -> + b3 -> out (f32)
  {
    const unsigned short* w3t = wt + 98304;
    f32x4 acc[2][4] = {};
    #pragma unroll
    for (int kk = 0; kk < 8; ++kk){
      int kb = kk * 32 + lg * 8;
      bf16x8 a0 = *(const bf16x8*)&h2s[((     lr) * H2DIM + kb) ^ sw];
      bf16x8 a1 = *(const bf16x8*)&h2s[((16 + lr) * H2DIM + kb) ^ sw];
      #pragma unroll
      for (int nn = 0; nn < 4; ++nn){
        bf16x8 b = *(const bf16x8*)&w3t[(w * 64 + nn * 16 + lr) * H2DIM + kb];
        acc[0][nn] = __builtin_amdgcn_mfma_f32_16x16x32_bf16(a0, b, acc[0][nn], 0, 0, 0);
        acc[1][nn] = __builtin_amdgcn_mfma_f32_16x16x32_bf16(a1, b, acc[1][nn], 0, 0, 0);
      }
    }
    float* ob = out + (((size_t)strm * NBATCH + n) * LPTS + l0) * CDIM;
    #pragma unroll
    for (int nn = 0; nn < 4; ++nn){
      int col = w * 64 + nn * 16 + lr;
      float bias = b3[col];
      #pragma unroll
      for (int m = 0; m < 2; ++m){
        #pragma unroll
        for (int r = 0; r < 4; ++r){
          int row = m * 16 + lg * 4 + r;
          ob[row * CDIM + col] = acc[m][nn][r] + bias;
        }
      }
    }
  }
}

extern "C" void kernel_launch(void* const* d_in, const int* in_sizes, int n_in,
                              void* d_out, int out_size, void* d_ws, size_t ws_size,
                              hipStream_t stream){
  const float* feat0 = (const float*)d_in[0];
  const float* feat1 = (const float*)d_in[1];
  const float* pts0  = (const float*)d_in[2];
  const float* pts1  = (const float*)d_in[3];
  const int*   anci  = (const int*)d_in[4];
  const int*   ancj  = (const int*)d_in[5];
  const float* W1    = (const float*)d_in[6];
  const float* b1    = (const float*)d_in[7];
  const float* W2    = (const float*)d_in[8];
  const float* b2    = (const float*)d_in[9];
  const float* W3    = (const float*)d_in[10];
  const float* b3    = (const float*)d_in[11];
  unsigned short* wt = (unsigned short*)d_ws;
  float* out = (float*)d_out;

  prep_weights<<<640, 256, 0, stream>>>(W1, W2, W3, wt);
  fused<<<8192, 256, 0, stream>>>(feat0, feat1, pts0, pts1, anci, ancj,
                                  b1, b2, b3, wt, out);
}

// Round 4
// 346.827 us; speedup vs baseline: 1.0653x; 1.0384x over previous
//
#include <hip/hip_runtime.h>

typedef __bf16 bf16x8 __attribute__((ext_vector_type(8)));
typedef float f32x4 __attribute__((ext_vector_type(4)));
typedef unsigned short u16x8 __attribute__((ext_vector_type(8)));

#define NBATCH 8
#define LPTS   16384
#define CDIM   256
#define KANC   64
#define DIN    512
#define H1DIM  128
#define H2DIM  256
#define TM     64

__device__ __forceinline__ unsigned short f2b(float f){
  __bf16 h = (__bf16)f;                 // native v_cvt, RNE
  return __builtin_bit_cast(unsigned short, h);
}

// wt[0..65536) = W1T[128][512]; wt[65536..98304) = W2T[256][128];
// wt[98304..163840) = W3T[256][256]   (all bf16)
__global__ __launch_bounds__(256) void prep_weights(
    const float* __restrict__ W1, const float* __restrict__ W2,
    const float* __restrict__ W3, unsigned short* __restrict__ wt){
  int id = blockIdx.x * 256 + threadIdx.x;
  if (id < 65536){
    int r = id >> 9, c = id & 511;
    wt[id] = f2b(W1[c * 128 + r]);
  } else if (id < 98304){
    int t = id - 65536; int r = t >> 7, c = t & 127;
    wt[id] = f2b(W2[c * 256 + r]);
  } else if (id < 163840){
    int t = id - 98304; int r = t >> 8, c = t & 255;
    wt[id] = f2b(W3[c * 256 + r]);
  }
}

// TM=64, 512 threads (8 waves, 2M x 4N), LDS 80 KiB -> 2 blocks/CU.
__global__ __launch_bounds__(512, 4) void fused(
    const float* __restrict__ feat0, const float* __restrict__ feat1,
    const float* __restrict__ pts0, const float* __restrict__ pts1,
    const int* __restrict__ anc_i, const int* __restrict__ anc_j,
    const float* __restrict__ b1, const float* __restrict__ b2,
    const float* __restrict__ b3, const unsigned short* __restrict__ wt,
    float* __restrict__ out)
{
  __shared__ unsigned short xs[TM * DIN];     // 64 KiB
  __shared__ unsigned short h1s[TM * H1DIM];  // 16 KiB
  unsigned short* h2s = xs;                   // xs dead (as input) after G1
  float4* anc4 = (float4*)h1s;                // padded 72 float4, dead pre-h1

  const int tid  = threadIdx.x;
  const int wg   = blockIdx.x;
  const int strm = wg >> 11;
  const int n    = (wg >> 8) & 7;
  const int l0   = (wg & 255) * TM;

  const float* feat = strm ? feat1 : feat0;
  const float* pts  = strm ? pts1 : pts0;
  const int*   anci = strm ? anc_j : anc_i;

  const int lane = tid & 63;
  const int w    = tid >> 6;
  const int wr   = w >> 2, wc = w & 3;
  const int lr   = lane & 15, lg = lane >> 4;
  const int r0   = wr * 32;
  const int sw   = (lr & 7) << 3;

  // ---- top-of-kernel prefetches (latency hides under Phases A/B) ----
  const float* pp = pts + ((size_t)n * LPTS + l0 + (tid >> 3)) * 3;
  float px = pp[0], py = pp[1], pz = pp[2];

  float bias1[2], bias2[4], bias3[4];
  #pragma unroll
  for (int nn = 0; nn < 2; ++nn) bias1[nn] = b1[wc * 32 + nn * 16 + lr];
  #pragma unroll
  for (int nn = 0; nn < 4; ++nn) bias2[nn] = b2[wc * 64 + nn * 16 + lr];
  #pragma unroll
  for (int nn = 0; nn < 4; ++nn) bias3[nn] = b3[wc * 64 + nn * 16 + lr];

  const unsigned short* bp0 = wt + (wc * 32      + lr) * DIN;
  const unsigned short* bp1 = wt + (wc * 32 + 16 + lr) * DIN;
  bf16x8 g1b0 = *(const bf16x8*)&bp0[lg * 8];       // GEMM1 B(kk=0)
  bf16x8 g1b1 = *(const bf16x8*)&bp1[lg * 8];

  // ---- anchors -> LDS (stride-9 padded: bank-conflict-free) ----
  if (tid < KANC){
    int ai = anci[n * KANC + tid];
    const float* ap = pts + ((size_t)n * LPTS + ai) * 3;
    anc4[tid + (tid >> 3)] = make_float4(ap[0], ap[1], ap[2], 0.f);
  }
  __syncthreads();

  // ---- Phase A: feat tile -> xs[:,0:256) ----
  {
    const float4* fb = (const float4*)(feat + ((size_t)n * LPTS + l0) * CDIM);
    #pragma unroll
    for (int it = 0; it < 4; ++it){
      int chunk = it * 512 + tid;       // 2048 8-float chunks per tile
      int r = chunk >> 5, c8 = chunk & 31;
      float4 a = fb[chunk * 2], b = fb[chunk * 2 + 1];
      u16x8 pk = { f2b(a.x), f2b(a.y), f2b(a.z), f2b(a.w),
                   f2b(b.x), f2b(b.y), f2b(b.z), f2b(b.w) };
      int e = (r * DIN + c8 * 8) ^ ((r & 7) << 3);
      *(u16x8*)&xs[e] = pk;
    }
  }

  // ---- Phase B: structured features -> xs[:,256:512) ----
  {
    const int l   = tid >> 3;
    const int sub = tid & 7;
    float s0 = 0.f, s1 = 0.f, s2 = 0.f, s3 = 0.f;
    #pragma unroll
    for (int i = 0; i < 8; ++i){
      float4 a = anc4[sub * 9 + i];
      float dx = px - a.x, dy = py - a.y, dz = pz - a.z;
      float d2 = dx*dx + dy*dy + dz*dz;
      s0 += fabsf(dx); s1 += fabsf(dy); s2 += fabsf(dz); s3 += d2;
    }
    #pragma unroll
    for (int m = 1; m <= 4; m <<= 1){
      s0 += __shfl_xor(s0, m, 64);
      s1 += __shfl_xor(s1, m, 64);
      s2 += __shfl_xor(s2, m, 64);
      s3 += __shfl_xor(s3, m, 64);
    }
    float i0 = 1.f/s0, i1 = 1.f/s1, i2 = 1.f/s2, i3 = 1.f/s3;

    u16x8 o0, o1, o2, o3;
    #pragma unroll
    for (int i = 0; i < 8; ++i){
      float4 a = anc4[sub * 9 + i];
      float dx = px - a.x, dy = py - a.y, dz = pz - a.z;
      float d2 = dx*dx + dy*dy + dz*dz;
      o0[i] = f2b(dx * i0); o1[i] = f2b(dy * i1);
      o2[i] = f2b(dz * i2); o3[i] = f2b(d2 * i3);
    }
    int base = l * DIN + 256 + sub * 8;
    int swl = (l & 7) << 3;
    *(u16x8*)&xs[(base      ) ^ swl] = o0;
    *(u16x8*)&xs[(base +  64) ^ swl] = o1;
    *(u16x8*)&xs[(base + 128) ^ swl] = o2;
    *(u16x8*)&xs[(base + 192) ^ swl] = o3;
  }
  __syncthreads();

  // ---- GEMM1: xs[64,512] @ W1 -> relu -> h1s[64,128] ----
  const unsigned short* w2t = wt + 65536;
  bf16x8 g2b[4];
  {
    f32x4 acc[2][2] = {};
    bf16x8 b0c = g1b0, b1c = g1b1;
    bf16x8 a0c = *(const bf16x8*)&xs[((r0      + lr) * DIN + lg * 8) ^ sw];
    bf16x8 a1c = *(const bf16x8*)&xs[((r0 + 16 + lr) * DIN + lg * 8) ^ sw];
    #pragma unroll
    for (int kk = 0; kk < 16; ++kk){
      bf16x8 a0n, a1n, b0n, b1n;
      if (kk < 15){
        int kbn = (kk + 1) * 32 + lg * 8;
        a0n = *(const bf16x8*)&xs[((r0      + lr) * DIN + kbn) ^ sw];
        a1n = *(const bf16x8*)&xs[((r0 + 16 + lr) * DIN + kbn) ^ sw];
        b0n = *(const bf16x8*)&bp0[kbn];
        b1n = *(const bf16x8*)&bp1[kbn];
      }
      acc[0][0] = __builtin_amdgcn_mfma_f32_16x16x32_bf16(a0c, b0c, acc[0][0], 0, 0, 0);
      acc[0][1] = __builtin_amdgcn_mfma_f32_16x16x32_bf16(a0c, b1c, acc[0][1], 0, 0, 0);
      acc[1][0] = __builtin_amdgcn_mfma_f32_16x16x32_bf16(a1c, b0c, acc[1][0], 0, 0, 0);
      acc[1][1] = __builtin_amdgcn_mfma_f32_16x16x32_bf16(a1c, b1c, acc[1][1], 0, 0, 0);
      if (kk < 15){ a0c = a0n; a1c = a1n; b0c = b0n; b1c = b1n; }
    }
    // prefetch GEMM2 B(kk=0) — hides under epilogue + barrier
    #pragma unroll
    for (int nn = 0; nn < 4; ++nn)
      g2b[nn] = *(const bf16x8*)&w2t[(wc * 64 + nn * 16 + lr) * H1DIM + lg * 8];
    #pragma unroll
    for (int nn = 0; nn < 2; ++nn){
      #pragma unroll
      for (int m = 0; m < 2; ++m){
        #pragma unroll
        for (int r = 0; r < 4; ++r){
          int row = r0 + m * 16 + lg * 4 + r;
          float v = fmaxf(acc[m][nn][r] + bias1[nn], 0.f);
          h1s[(row * H1DIM + wc * 32 + nn * 16 + lr) ^ ((row & 7) << 3)] = f2b(v);
        }
      }
    }
  }
  __syncthreads();

  // ---- GEMM2: h1s[64,128] @ W2 -> relu -> h2s[64,256] ----
  const unsigned short* w3t = wt + 98304;
  bf16x8 g3b[4];
  {
    f32x4 acc[2][4] = {};
    bf16x8 bc[4] = { g2b[0], g2b[1], g2b[2], g2b[3] };
    bf16x8 a0c = *(const bf16x8*)&h1s[((r0      + lr) * H1DIM + lg * 8) ^ sw];
    bf16x8 a1c = *(const bf16x8*)&h1s[((r0 + 16 + lr) * H1DIM + lg * 8) ^ sw];
    #pragma unroll
    for (int kk = 0; kk < 4; ++kk){
      bf16x8 a0n, a1n, bn[4];
      if (kk < 3){
        int kbn = (kk + 1) * 32 + lg * 8;
        a0n = *(const bf16x8*)&h1s[((r0      + lr) * H1DIM + kbn) ^ sw];
        a1n = *(const bf16x8*)&h1s[((r0 + 16 + lr) * H1DIM + kbn) ^ sw];
        #pragma unroll
        for (int nn = 0; nn < 4; ++nn)
          bn[nn] = *(const bf16x8*)&w2t[(wc * 64 + nn * 16 + lr) * H1DIM + kbn];
      }
      #pragma unroll
      for (int nn = 0; nn < 4; ++nn){
        acc[0][nn] = __builtin_amdgcn_mfma_f32_16x16x32_bf16(a0c, bc[nn], acc[0][nn], 0, 0, 0);
        acc[1][nn] = __builtin_amdgcn_mfma_f32_16x16x32_bf16(a1c, bc[nn], acc[1][nn], 0, 0, 0);
      }
      if (kk < 3){
        a0c = a0n; a1c = a1n;
        #pragma unroll
        for (int nn = 0; nn < 4; ++nn) bc[nn] = bn[nn];
      }
    }
    // prefetch GEMM3 B(kk=0)
    #pragma unroll
    for (int nn = 0; nn < 4; ++nn)
      g3b[nn] = *(const bf16x8*)&w3t[(wc * 64 + nn * 16 + lr) * H2DIM + lg * 8];
    #pragma unroll
    for (int nn = 0; nn < 4; ++nn){
      #pragma unroll
      for (int m = 0; m < 2; ++m){
        #pragma unroll
        for (int r = 0; r < 4; ++r){
          int row = r0 + m * 16 + lg * 4 + r;
          float v = fmaxf(acc[m][nn][r] + bias2[nn], 0.f);
          h2s[(row * H2DIM + wc * 64 + nn * 16 + lr) ^ ((row & 7) << 3)] = f2b(v);
        }
      }
    }
  }
  __syncthreads();

  // ---- GEMM3: h2s[64,256] @ W3 -> + b3 -> out (f32) ----
  {
    f32x4 acc[2][4] = {};
    bf16x8 bc[4] = { g3b[0], g3b[1], g3b[2], g3b[3] };
    bf16x8 a0c = *(const bf16x8*)&h2s[((r0      + lr) * H2DIM + lg * 8) ^ sw];
    bf16x8 a1c = *(const bf16x8*)&h2s[((r0 + 16 + lr) * H2DIM + lg * 8) ^ sw];
    #pragma unroll
    for (int kk = 0; kk < 8; ++kk){
      bf16x8 a0n, a1n, bn[4];
      if (kk < 7){
        int kbn = (kk + 1) * 32 + lg * 8;
        a0n = *(const bf16x8*)&h2s[((r0      + lr) * H2DIM + kbn) ^ sw];
        a1n = *(const bf16x8*)&h2s[((r0 + 16 + lr) * H2DIM + kbn) ^ sw];
        #pragma unroll
        for (int nn = 0; nn < 4; ++nn)
          bn[nn] = *(const bf16x8*)&w3t[(wc * 64 + nn * 16 + lr) * H2DIM + kbn];
      }
      #pragma unroll
      for (int nn = 0; nn < 4; ++nn){
        acc[0][nn] = __builtin_amdgcn_mfma_f32_16x16x32_bf16(a0c, bc[nn], acc[0][nn], 0, 0, 0);
        acc[1][nn] = __builtin_amdgcn_mfma_f32_16x16x32_bf16(a1c, bc[nn], acc[1][nn], 0, 0, 0);
      }
      if (kk < 7){
        a0c = a0n; a1c = a1n;
        #pragma unroll
        for (int nn = 0; nn < 4; ++nn) bc[nn] = bn[nn];
      }
    }
    float* ob = out + (((size_t)strm * NBATCH + n) * LPTS + l0) * CDIM;
    #pragma unroll
    for (int nn = 0; nn < 4; ++nn){
      int col = wc * 64 + nn * 16 + lr;
      #pragma unroll
      for (int m = 0; m < 2; ++m){
        #pragma unroll
        for (int r = 0; r < 4; ++r){
          int row = r0 + m * 16 + lg * 4 + r;
          ob[row * CDIM + col] = acc[m][nn][r] + bias3[nn];
        }
      }
    }
  }
}

extern "C" void kernel_launch(void* const* d_in, const int* in_sizes, int n_in,
                              void* d_out, int out_size, void* d_ws, size_t ws_size,
                              hipStream_t stream){
  const float* feat0 = (const float*)d_in[0];
  const float* feat1 = (const float*)d_in[1];
  const float* pts0  = (const float*)d_in[2];
  const float* pts1  = (const float*)d_in[3];
  const int*   anci  = (const int*)d_in[4];
  const int*   ancj  = (const int*)d_in[5];
  const float* W1    = (const float*)d_in[6];
  const float* b1    = (const float*)d_in[7];
  const float* W2    = (const float*)d_in[8];
  const float* b2    = (const float*)d_in[9];
  const float* W3    = (const float*)d_in[10];
  const float* b3    = (const float*)d_in[11];
  unsigned short* wt = (unsigned short*)d_ws;
  float* out = (float*)d_out;

  prep_weights<<<640, 256, 0, stream>>>(W1, W2, W3, wt);
  fused<<<4096, 512, 0, stream>>>(feat0, feat1, pts0, pts1, anci, ancj,
                                  b1, b2, b3, wt, out);
}

// Round 5
// 226.913 us; speedup vs baseline: 1.6283x; 1.5285x over previous
//
#include <hip/hip_runtime.h>

typedef __bf16 bf16x8 __attribute__((ext_vector_type(8)));
typedef float f32x4 __attribute__((ext_vector_type(4)));
typedef unsigned short u16x4 __attribute__((ext_vector_type(4)));
typedef unsigned short u16x8 __attribute__((ext_vector_type(8)));

#define NBATCH 8
#define LPTS   16384
#define CDIM   256
#define KANC   64
#define DIN    512
#define H1DIM  128
#define H2DIM  256
#define TM     64

__device__ __forceinline__ unsigned short f2b(float f){
  __bf16 h = (__bf16)f;                 // native v_cvt, RNE
  return __builtin_bit_cast(unsigned short, h);
}

// wt[0..65536) = W1T[128][512]; wt[65536..98304) = W2T[256][128];
// wt[98304..163840) = W3T[256][256]   (all bf16)
__global__ __launch_bounds__(256) void prep_weights(
    const float* __restrict__ W1, const float* __restrict__ W2,
    const float* __restrict__ W3, unsigned short* __restrict__ wt){
  int id = blockIdx.x * 256 + threadIdx.x;
  if (id < 65536){
    int r = id >> 9, c = id & 511;
    wt[id] = f2b(W1[c * 128 + r]);
  } else if (id < 98304){
    int t = id - 65536; int r = t >> 7, c = t & 127;
    wt[id] = f2b(W2[c * 256 + r]);
  } else if (id < 163840){
    int t = id - 98304; int r = t >> 8, c = t & 255;
    wt[id] = f2b(W3[c * 256 + r]);
  }
}

__global__ __launch_bounds__(512, 4) void fused(
    const float* __restrict__ feat0, const float* __restrict__ feat1,
    const float* __restrict__ pts0, const float* __restrict__ pts1,
    const int* __restrict__ anc_i, const int* __restrict__ anc_j,
    const float* __restrict__ b1, const float* __restrict__ b2,
    const float* __restrict__ b3, const unsigned short* __restrict__ wt,
    float* __restrict__ out)
{
  // 80 KiB total -> 2 blocks/CU. h2 aliases xs (xs dead after GEMM1);
  // anc4 aliases h1s (anchors dead before h1s first written).
  __shared__ unsigned short xs[TM * DIN];     // 64 KiB
  __shared__ unsigned short h1s[TM * H1DIM];  // 16 KiB
  unsigned short* h2s = xs;
  float4* anc4 = (float4*)h1s;                // stride-9 padded: 72 float4

  const int tid  = threadIdx.x;
  const int wg   = blockIdx.x;
  const int strm = wg >> 11;
  const int n    = (wg >> 8) & 7;
  const int l0   = (wg & 255) * TM;

  const float* feat = strm ? feat1 : feat0;
  const float* pts  = strm ? pts1 : pts0;
  const int*   anci = strm ? anc_j : anc_i;

  // hoisted pts load for Phase B (latency hides under Phase A)
  const float* pp = pts + ((size_t)n * LPTS + l0 + (tid >> 3)) * 3;
  float px = pp[0], py = pp[1], pz = pp[2];

  // anchors -> LDS (stride-9 padded float4: conflict-free)
  if (tid < KANC){
    int ai = anci[n * KANC + tid];
    const float* ap = pts + ((size_t)n * LPTS + ai) * 3;
    anc4[tid + (tid >> 3)] = make_float4(ap[0], ap[1], ap[2], 0.f);
  }

  // ---- Phase A: feat tile -> xs[:, 0:256) (bf16, swizzled) — R0 verbatim
  {
    const float4* fb = (const float4*)(feat + ((size_t)n * LPTS + l0) * CDIM);
    #pragma unroll
    for (int it = 0; it < 8; ++it){
      int flat = it * 512 + tid;          // 4096 float4 in tile, 16B/lane coalesced
      int r = flat >> 6, c4 = flat & 63;
      float4 v = fb[flat];
      int e = (r * DIN + c4 * 4) ^ ((r & 7) << 3);
      u16x4 pk = { f2b(v.x), f2b(v.y), f2b(v.z), f2b(v.w) };
      *(u16x4*)&xs[e] = pk;
    }
  }
  __syncthreads();

  // ---- Phase B: structured features -> xs[:, 256:512)
  // wave-parallel: 8 threads/point, 8 anchors each, shfl_xor L1 reduce.
  {
    const int l   = tid >> 3;             // 0..63
    const int sub = tid & 7;
    float s0 = 0.f, s1 = 0.f, s2 = 0.f, s3 = 0.f;
    #pragma unroll
    for (int i = 0; i < 8; ++i){
      float4 a = anc4[sub * 9 + i];
      float dx = px - a.x, dy = py - a.y, dz = pz - a.z;
      float d2 = dx*dx + dy*dy + dz*dz;
      s0 += fabsf(dx); s1 += fabsf(dy); s2 += fabsf(dz); s3 += d2;
    }
    #pragma unroll
    for (int m = 1; m <= 4; m <<= 1){
      s0 += __shfl_xor(s0, m, 64);
      s1 += __shfl_xor(s1, m, 64);
      s2 += __shfl_xor(s2, m, 64);
      s3 += __shfl_xor(s3, m, 64);
    }
    float i0 = 1.f/s0, i1 = 1.f/s1, i2 = 1.f/s2, i3 = 1.f/s3;

    u16x8 o0, o1, o2, o3;
    #pragma unroll
    for (int i = 0; i < 8; ++i){
      float4 a = anc4[sub * 9 + i];
      float dx = px - a.x, dy = py - a.y, dz = pz - a.z;
      float d2 = dx*dx + dy*dy + dz*dz;
      o0[i] = f2b(dx * i0); o1[i] = f2b(dy * i1);
      o2[i] = f2b(dz * i2); o3[i] = f2b(d2 * i3);
    }
    int base = l * DIN + 256 + sub * 8;
    int swl = (l & 7) << 3;
    *(u16x8*)&xs[(base      ) ^ swl] = o0;
    *(u16x8*)&xs[(base +  64) ^ swl] = o1;
    *(u16x8*)&xs[(base + 128) ^ swl] = o2;
    *(u16x8*)&xs[(base + 192) ^ swl] = o3;
  }
  __syncthreads();

  const int lane = tid & 63;
  const int w    = tid >> 6;
  const int lr   = lane & 15;
  const int lg   = lane >> 4;

  // ---- GEMM1: xs[64,512] @ W1 -> relu -> h1s[64,128]  — R0 verbatim
  {
    f32x4 acc[4] = {};
    const int col = w * 16 + lr;                  // wave owns 16 cols
    const unsigned short* wrow = wt + col * DIN;
    #pragma unroll 4
    for (int kk = 0; kk < 16; ++kk){
      int kb = kk * 32 + lg * 8;
      bf16x8 b = *(const bf16x8*)&wrow[kb];
      #pragma unroll
      for (int m = 0; m < 4; ++m){
        int row = m * 16 + lr;
        int e = (row * DIN + kb) ^ ((row & 7) << 3);
        bf16x8 a = *(const bf16x8*)&xs[e];
        acc[m] = __builtin_amdgcn_mfma_f32_16x16x32_bf16(a, b, acc[m], 0, 0, 0);
      }
    }
    float bias = b1[col];
    #pragma unroll
    for (int m = 0; m < 4; ++m){
      #pragma unroll
      for (int r = 0; r < 4; ++r){
        int row = m * 16 + lg * 4 + r;
        float v = fmaxf(acc[m][r] + bias, 0.f);
        int e = (row * H1DIM + col) ^ ((row & 7) << 3);
        h1s[e] = f2b(v);
      }
    }
  }
  __syncthreads();

  // ---- GEMM2: h1s[64,128] @ W2 -> relu -> h2s[64,256]  — R0 verbatim
  {
    const unsigned short* w2t = wt + 65536;
    f32x4 acc[4][2] = {};
    const int col0 = w * 32;
    #pragma unroll
    for (int kk = 0; kk < 4; ++kk){
      int kb = kk * 32 + lg * 8;
      bf16x8 bf0 = *(const bf16x8*)&w2t[(col0 + lr) * H1DIM + kb];
      bf16x8 bf1 = *(const bf16x8*)&w2t[(col0 + 16 + lr) * H1DIM + kb];
      #pragma unroll
      for (int m = 0; m < 4; ++m){
        int row = m * 16 + lr;
        int e = (row * H1DIM + kb) ^ ((row & 7) << 3);
        bf16x8 a = *(const bf16x8*)&h1s[e];
        acc[m][0] = __builtin_amdgcn_mfma_f32_16x16x32_bf16(a, bf0, acc[m][0], 0, 0, 0);
        acc[m][1] = __builtin_amdgcn_mfma_f32_16x16x32_bf16(a, bf1, acc[m][1], 0, 0, 0);
      }
    }
    __syncthreads();   // all h1s reads done AND xs (GEMM1 A-reads) fully retired
    #pragma unroll
    for (int nt = 0; nt < 2; ++nt){
      int col = col0 + nt * 16 + lr;
      float bias = b2[col];
      #pragma unroll
      for (int m = 0; m < 4; ++m){
        #pragma unroll
        for (int r = 0; r < 4; ++r){
          int row = m * 16 + lg * 4 + r;
          float v = fmaxf(acc[m][nt][r] + bias, 0.f);
          int e = (row * H2DIM + col) ^ ((row & 7) << 3);
          h2s[e] = f2b(v);
        }
      }
    }
  }
  __syncthreads();

  // ---- GEMM3: h2s[64,256] @ W3 -> + b3 -> out (f32)  — R0 verbatim
  {
    const unsigned short* w3t = wt + 98304;
    f32x4 acc[4][2] = {};
    const int col0 = w * 32;
    #pragma unroll 4
    for (int kk = 0; kk < 8; ++kk){
      int kb = kk * 32 + lg * 8;
      bf16x8 bf0 = *(const bf16x8*)&w3t[(col0 + lr) * H2DIM + kb];
      bf16x8 bf1 = *(const bf16x8*)&w3t[(col0 + 16 + lr) * H2DIM + kb];
      #pragma unroll
      for (int m = 0; m < 4; ++m){
        int row = m * 16 + lr;
        int e = (row * H2DIM + kb) ^ ((row & 7) << 3);
        bf16x8 a = *(const bf16x8*)&h2s[e];
        acc[m][0] = __builtin_amdgcn_mfma_f32_16x16x32_bf16(a, bf0, acc[m][0], 0, 0, 0);
        acc[m][1] = __builtin_amdgcn_mfma_f32_16x16x32_bf16(a, bf1, acc[m][1], 0, 0, 0);
      }
    }
    float* ob = out + (((size_t)strm * NBATCH + n) * LPTS + l0) * CDIM;
    #pragma unroll
    for (int nt = 0; nt < 2; ++nt){
      int col = col0 + nt * 16 + lr;
      float bias = b3[col];
      #pragma unroll
      for (int m = 0; m < 4; ++m){
        #pragma unroll
        for (int r = 0; r < 4; ++r){
          int row = m * 16 + lg * 4 + r;
          ob[(size_t)row * CDIM + col] = acc[m][nt][r] + bias;
        }
      }
    }
  }
}

extern "C" void kernel_launch(void* const* d_in, const int* in_sizes, int n_in,
                              void* d_out, int out_size, void* d_ws, size_t ws_size,
                              hipStream_t stream){
  const float* feat0 = (const float*)d_in[0];
  const float* feat1 = (const float*)d_in[1];
  const float* pts0  = (const float*)d_in[2];
  const float* pts1  = (const float*)d_in[3];
  const int*   anci  = (const int*)d_in[4];
  const int*   ancj  = (const int*)d_in[5];
  const float* W1    = (const float*)d_in[6];
  const float* b1    = (const float*)d_in[7];
  const float* W2    = (const float*)d_in[8];
  const float* b2    = (const float*)d_in[9];
  const float* W3    = (const float*)d_in[10];
  const float* b3    = (const float*)d_in[11];
  unsigned short* wt = (unsigned short*)d_ws;
  float* out = (float*)d_out;

  prep_weights<<<640, 256, 0, stream>>>(W1, W2, W3, wt);
  fused<<<4096, 512, 0, stream>>>(feat0, feat1, pts0, pts1, anci, ancj,
                                  b1, b2, b3, wt, out);
}